// Round 14
// baseline (391.024 us; speedup 1.0000x reference)
//
#include <hip/hip_runtime.h>

// Fixed problem sizes: b=4, c=256, n=4096, cr=32.
#define Bb 4
#define Cc 256
#define Nn 4096
#define CR 32
#define EPS_BN 1e-5f
// Fixed-shift softmax: scores >= 0 (post-ReLU Q,K), bounded << 100, so
// exp(s-20) is exactly softmax-equivalent and overflow/underflow safe.
// K is pre-scaled by log2(e) in qkv, so attn uses exp2(s' - 20*log2e).
#define SHIFT2 28.853900817779268f
#define LOG2E  1.4426950408889634f
#define JSPLIT 2
#define JSL (Nn / JSPLIT)    // 2048 j per attention block
#define JT32 (JSL / 32)      // 64 j-steps of 32

typedef __attribute__((ext_vector_type(8))) short short8;   // 8 bf16
typedef __attribute__((ext_vector_type(4))) float f32x4;
typedef __attribute__((ext_vector_type(4))) int int4v;

__device__ inline unsigned int pk2(float a, float b) {
    __bf16 ha = (__bf16)a, hb = (__bf16)b;
    unsigned short ra = __builtin_bit_cast(unsigned short, ha);
    unsigned short rb = __builtin_bit_cast(unsigned short, hb);
    return ((unsigned int)rb << 16) | ra;
}
__device__ inline float blo(unsigned int u) { return __uint_as_float(u << 16); }
__device__ inline float bhi(unsigned int u) { return __uint_as_float(u & 0xffff0000u); }
__device__ inline float ex2(float x) { return __builtin_amdgcn_exp2f(x); }

// ---------------------------------------------------------------------------
// Kernel 0 (R13): fused preprocessing. Planes y=0..3: split-bf16 transpose of
// x -> xhi/xlo [b][n][c]. Plane y=4 (z=0, x<20): pack W into frag-major Wf.
// grid (64, 5, 4), 256 threads.
// ---------------------------------------------------------------------------
__global__ __launch_bounds__(256) void prep_kernel(
    const float* __restrict__ x,
    __bf16* __restrict__ xhi, __bf16* __restrict__ xlo,
    const float* __restrict__ wq, const float* __restrict__ wk,
    const float* __restrict__ wv, __bf16* __restrict__ Wf)
{
    __shared__ __align__(16) float tile[64][68];   // 17.4 KB
    const int tid = threadIdx.x;

    if (blockIdx.y == 4) {
        if (blockIdx.z != 0 || blockIdx.x >= 20) return;
        const int r16 = blockIdx.x;                 // 0..19
#pragma unroll
        for (int ss = 0; ss < 2; ++ss) {
            int s = tid + ss * 256;                 // 0..511 = (kc 8) x (lane 64)
            int kc = s >> 6, lane = s & 63;
            int R = r16 * 16 + (lane & 15);
            const float* src = (R < 32) ? (wq + (size_t)R * Cc)
                             : (R < 64) ? (wk + (size_t)(R - 32) * Cc)
                                        : (wv + (size_t)(R - 64) * Cc);
            const float* p = src + kc * 32 + (lane >> 4) * 8;
            float4 a = *(const float4*)p;
            float4 c2 = *(const float4*)(p + 4);
            uint4 pk = { pk2(a.x,a.y), pk2(a.z,a.w), pk2(c2.x,c2.y), pk2(c2.z,c2.w) };
            *(uint4*)&Wf[(((size_t)r16 * 8 + kc) * 64 + lane) * 8] = pk;
        }
        return;
    }

    const int n0 = blockIdx.x * 64, c0 = blockIdx.y * 64, b = blockIdx.z;

    {
        int r = tid >> 2, q = tid & 3;
        const float* src = &x[(size_t)(b * Cc + c0 + r) * Nn + n0 + q * 16];
#pragma unroll
        for (int u = 0; u < 4; ++u)
            *(float4*)&tile[r][q * 16 + u * 4] = *(const float4*)&src[u * 4];
    }
    __syncthreads();

    {
        int nr = tid >> 2, oc = tid & 3;
        uint4 H[2], L[2];
#pragma unroll
        for (int u = 0; u < 2; ++u) {
            float h[8], lo8[8];
#pragma unroll
            for (int j = 0; j < 8; ++j) {
                float v = tile[oc * 16 + u * 8 + j][nr];
                float hh = (float)(__bf16)v;
                h[j] = hh; lo8[j] = v - hh;
            }
            H[u] = (uint4){ pk2(h[0],h[1]), pk2(h[2],h[3]), pk2(h[4],h[5]), pk2(h[6],h[7]) };
            L[u] = (uint4){ pk2(lo8[0],lo8[1]), pk2(lo8[2],lo8[3]), pk2(lo8[4],lo8[5]), pk2(lo8[6],lo8[7]) };
        }
        size_t base = (size_t)(b * Nn + n0 + nr) * Cc + c0 + oc * 16;
        *(uint4*)&xhi[base]     = H[0];
        *(uint4*)&xhi[base + 8] = H[1];
        *(uint4*)&xlo[base]     = L[0];
        *(uint4*)&xlo[base + 8] = L[1];
    }
}

// ---------------------------------------------------------------------------
// Kernel 1 (R11): QKV = BN_ReLU(W x) as a pure global-operand GEMM.
// grid (32 n-tiles, 3 groups, 4 b), block 256.
// ---------------------------------------------------------------------------
__global__ __launch_bounds__(256) void qkv_kernel(
    const __bf16* __restrict__ xhi, const __bf16* __restrict__ xlo,
    const __bf16* __restrict__ Wf,
    const float* __restrict__ bn1s, const float* __restrict__ bn1b, const float* __restrict__ bn1m, const float* __restrict__ bn1v,
    const float* __restrict__ bn2s, const float* __restrict__ bn2b, const float* __restrict__ bn2m, const float* __restrict__ bn2v,
    const float* __restrict__ bn3s, const float* __restrict__ bn3b, const float* __restrict__ bn3m, const float* __restrict__ bn3v,
    __bf16* __restrict__ Qt, __bf16* __restrict__ Kt, __bf16* __restrict__ Vb)
{
    __shared__ __align__(16) __bf16 oT[128 * 136];         // V epilogue, 34 KB

    const int tid = threadIdx.x;
    const int n0 = blockIdx.x * 128, g = blockIdx.y, b = blockIdx.z;
    const int lane = tid & 63, w = tid >> 6;
    const int l15 = lane & 15, l4 = lane >> 4;
    const int nmt = (g == 0) ? 4 : 8;                       // row-16-groups
    const int r16b = (g == 0) ? 0 : 4 + (g - 1) * 8;        // base into Wf

    const size_t bfoff = (size_t)(b * Nn + n0 + w * 32 + l15) * Cc + l4 * 8;
    const __bf16* bh0 = xhi + bfoff;
    const __bf16* bl0 = xlo + bfoff;

    f32x4 acc[8][2];
#pragma unroll
    for (int mt = 0; mt < 8; ++mt)
#pragma unroll
        for (int nt = 0; nt < 2; ++nt) acc[mt][nt] = (f32x4){0.f, 0.f, 0.f, 0.f};

    for (int kc = 0; kc < 8; ++kc) {
        short8 bh[2], bl[2];
#pragma unroll
        for (int nt = 0; nt < 2; ++nt) {
            bh[nt] = *(const short8*)&bh0[(size_t)(nt * 16) * Cc + kc * 32];
            bl[nt] = *(const short8*)&bl0[(size_t)(nt * 16) * Cc + kc * 32];
        }
#pragma unroll
        for (int mt = 0; mt < 8; ++mt) {
            if (mt < nmt) {
                short8 af = *(const short8*)&Wf[(((size_t)(r16b + mt) * 8 + kc) * 64 + lane) * 8];
#pragma unroll
                for (int nt = 0; nt < 2; ++nt) {
                    acc[mt][nt] = __builtin_amdgcn_mfma_f32_16x16x32_bf16(af, bh[nt], acc[mt][nt], 0, 0, 0);
                    acc[mt][nt] = __builtin_amdgcn_mfma_f32_16x16x32_bf16(af, bl[nt], acc[mt][nt], 0, 0, 0);
                }
            }
        }
    }

    if (g == 0) {
#pragma unroll
        for (int mt = 0; mt < 4; ++mt) {
            float scl[4], off[4];
#pragma unroll
            for (int r = 0; r < 4; ++r) {
                int R = mt * 16 + l4 * 4 + r;
                float s, o;
                if (R < 32) {
                    s = bn1s[R] * __frsqrt_rn(bn1v[R] + EPS_BN);
                    o = bn1b[R] - bn1m[R] * s;
                } else {
                    int row = R - 32;
                    s = bn2s[row] * __frsqrt_rn(bn2v[row] + EPS_BN);
                    o = bn2b[row] - bn2m[row] * s;
                    s *= LOG2E; o *= LOG2E;
                }
                scl[r] = s; off[r] = o;
            }
            __bf16* dst = (mt < 2) ? Qt : Kt;
            int d0 = (mt & 1) * 16 + l4 * 4;
#pragma unroll
            for (int nt = 0; nt < 2; ++nt) {
                f32x4 a = acc[mt][nt];
                float e0 = fmaxf(fmaf(a.x, scl[0], off[0]), 0.f);
                float e1 = fmaxf(fmaf(a.y, scl[1], off[1]), 0.f);
                float e2 = fmaxf(fmaf(a.z, scl[2], off[2]), 0.f);
                float e3 = fmaxf(fmaf(a.w, scl[3], off[3]), 0.f);
                uint2 p = { pk2(e0, e1), pk2(e2, e3) };
                int n = n0 + w * 32 + nt * 16 + l15;
                *(uint2*)&dst[(size_t)(b * Nn + n) * CR + d0] = p;
            }
        }
    } else {
        const int vr0 = (g - 1) * 128;
#pragma unroll
        for (int mt = 0; mt < 8; ++mt) {
            float scl[4], off[4];
#pragma unroll
            for (int r = 0; r < 4; ++r) {
                int row = vr0 + mt * 16 + l4 * 4 + r;
                float s = bn3s[row] * __frsqrt_rn(bn3v[row] + EPS_BN);
                scl[r] = s; off[r] = bn3b[row] - bn3m[row] * s;
            }
#pragma unroll
            for (int nt = 0; nt < 2; ++nt) {
                f32x4 a = acc[mt][nt];
                float e[4];
                e[0] = fmaxf(fmaf(a.x, scl[0], off[0]), 0.f);
                e[1] = fmaxf(fmaf(a.y, scl[1], off[1]), 0.f);
                e[2] = fmaxf(fmaf(a.z, scl[2], off[2]), 0.f);
                e[3] = fmaxf(fmaf(a.w, scl[3], off[3]), 0.f);
                int ncol = w * 32 + nt * 16 + l15;
#pragma unroll
                for (int r = 0; r < 4; ++r)
                    oT[(mt * 16 + l4 * 4 + r) * 136 + ncol] = (__bf16)e[r];
            }
        }
        __syncthreads();
        int rr = tid >> 1, qq = tid & 1;          // 128 rows x 2 n-halves
        size_t vrow = (size_t)(b * Cc + vr0 + rr) * Nn + n0 + qq * 64;
#pragma unroll
        for (int e8 = 0; e8 < 8; ++e8)
            *(uint4*)&Vb[vrow + e8 * 8] = *(const uint4*)&oT[rr * 136 + qq * 64 + e8 * 8];
    }
}

// ---------------------------------------------------------------------------
// Kernel 2 (R14): in-register-softmax attention -- ZERO LDS, ZERO barriers.
// Every prior variant (72-81us) shared P-through-LDS + lockstep barriers;
// this removes both (catalog SSB-attn structure). Wave owns 16 i x JSL j x
// 128 c (csplit=2). Per 32-j step:
//   S^T = mfma(K,Q): lane (i=l15, h') holds S[j=4h'+r][i] for 2 K-frags.
//   exp2 + pk2 in-register; lp accumulates per-lane (one i per lane).
//   PV A-frag assembly: lane (i,h) needs P[i][8h..8h+7]; uint w comes from
//   lane i+16*(2*(h&1) + (w>>1)) (u0 if w even, u1 if odd), q-tile by h>>1
//   -> 8 ds_bpermute + 4 cndmask (no LDS arrays, no syncs).
//   PV: 8 x mfma(paf, vf[ct]) into oacc (i rows x c cols, same C-layout).
// Waves are fully independent streams; K/V/Q read direct from L2.
// PO slot math reproduces the R0 layout -> reduce_kernel unchanged.
// grid (32 i-blks, js*2+cs = 4, 4 b) = 512 blocks, block 512 (8 waves).
// ---------------------------------------------------------------------------
__global__ __launch_bounds__(512) void attn_kernel(
    const __bf16* __restrict__ Qt, const __bf16* __restrict__ Kt,
    const __bf16* __restrict__ Vb,
    __bf16* __restrict__ PO, float* __restrict__ PL)
{
    const int tid = threadIdx.x, lane = tid & 63, w = tid >> 6;   // w 0..7
    const int b = blockIdx.z, iblk = blockIdx.x;
    const int js = blockIdx.y >> 1, cs = blockIdx.y & 1;
    const int l15 = lane & 15, l4 = lane >> 4;

    // Q B-frag for this wave's 16 i (held all kernel; direct global b128)
    const int i0 = iblk * 128 + w * 16;
    const short8 qf = *(const short8*)&Qt[(size_t)(b * Nn + i0 + l15) * CR + l4 * 8];

    f32x4 oacc[8];
#pragma unroll
    for (int z = 0; z < 8; ++z) oacc[z] = (f32x4){0.f, 0.f, 0.f, 0.f};
    float lp = 0.f;

    const size_t jb = (size_t)js * JSL;
    const __bf16* krow  = Kt + (size_t)(b * Nn + jb + l15) * CR + l4 * 8;
    const __bf16* vrow0 = Vb + (size_t)(b * Cc + cs * 128 + l15) * Nn + jb + l4 * 8;

    // bpermute source lanes (byte addresses): s0 = i + 32*(h&1), s1 = s0+16
    const int s0 = (l15 + ((l4 & 1) << 5)) << 2;
    const int s1 = s0 + 64;
    const bool hiq = (lane >= 32);       // h>=2 -> use q1 (j 16..31)

    short8 kf0 = *(const short8*)&krow[0];
    short8 kf1 = *(const short8*)&krow[16 * CR];

    for (int jt = 0; jt < JT32; ++jt) {
        const int joff = jt * 32;

        // V B-frags for this 32-j step (consumed after softmax; in flight
        // across QK + exp2 + bpermute)
        short8 vf[8];
#pragma unroll
        for (int ct = 0; ct < 8; ++ct)
            vf[ct] = *(const short8*)&vrow0[(size_t)(ct * 16) * Nn + joff];

        // prefetch next step's K A-frags
        short8 kn0 = kf0, kn1 = kf1;
        if (jt + 1 < JT32) {
            kn0 = *(const short8*)&krow[(joff + 32) * CR];
            kn1 = *(const short8*)&krow[(joff + 48) * CR];
        }

        // QK: S^T (32 j x 16 i), exp2, pack
        f32x4 c0 = (f32x4){0.f, 0.f, 0.f, 0.f};
        f32x4 c1 = (f32x4){0.f, 0.f, 0.f, 0.f};
        c0 = __builtin_amdgcn_mfma_f32_16x16x32_bf16(kf0, qf, c0, 0, 0, 0);
        c1 = __builtin_amdgcn_mfma_f32_16x16x32_bf16(kf1, qf, c1, 0, 0, 0);
        float e0 = ex2(c0.x - SHIFT2), e1 = ex2(c0.y - SHIFT2);
        float e2 = ex2(c0.z - SHIFT2), e3 = ex2(c0.w - SHIFT2);
        float f0 = ex2(c1.x - SHIFT2), f1 = ex2(c1.y - SHIFT2);
        float f2 = ex2(c1.z - SHIFT2), f3 = ex2(c1.w - SHIFT2);
        lp += ((e0 + e1) + (e2 + e3)) + ((f0 + f1) + (f2 + f3));
        int q0u0 = (int)pk2(e0, e1), q0u1 = (int)pk2(e2, e3);
        int q1u0 = (int)pk2(f0, f1), q1u1 = (int)pk2(f2, f3);

        // PV A-frag assembly via cross-lane pulls (4-lane i-group)
        int A0 = __builtin_amdgcn_ds_bpermute(s0, q0u0);
        int A1 = __builtin_amdgcn_ds_bpermute(s0, q0u1);
        int A2 = __builtin_amdgcn_ds_bpermute(s1, q0u0);
        int A3 = __builtin_amdgcn_ds_bpermute(s1, q0u1);
        int B0 = __builtin_amdgcn_ds_bpermute(s0, q1u0);
        int B1 = __builtin_amdgcn_ds_bpermute(s0, q1u1);
        int B2 = __builtin_amdgcn_ds_bpermute(s1, q1u0);
        int B3 = __builtin_amdgcn_ds_bpermute(s1, q1u1);
        int4v ww = { hiq ? B0 : A0, hiq ? B1 : A1, hiq ? B2 : A2, hiq ? B3 : A3 };
        short8 paf = __builtin_bit_cast(short8, ww);

        // PV: O[i][c] += P[i][32j] * V[32j][c]
#pragma unroll
        for (int ct = 0; ct < 8; ++ct)
            oacc[ct] = __builtin_amdgcn_mfma_f32_16x16x32_bf16(paf, vf[ct], oacc[ct], 0, 0, 0);

        kf0 = kn0; kf1 = kn1;
    }

    // lp: sum across the 4-lane i-group {i, i+16, i+32, i+48}
    lp += __shfl_xor(lp, 16);
    lp += __shfl_xor(lp, 32);
    if (cs == 0 && lane < 16)
        PL[(size_t)(js * Bb + b) * Nn + i0 + lane] = lp;

    // store partials in raw C-layout, bf16-packed (4 consecutive i per uint2)
    // i64-tile = 2*iblk + (w>>2); it = w&3; gc = cs*8+ct; slot reproduces R0.
    const size_t pbase = (size_t)((js * Bb + b) * (Nn / 64) + 2 * iblk + (w >> 2)) * 16384;
#pragma unroll
    for (int ct = 0; ct < 8; ++ct) {
        f32x4 a = oacc[ct];
        uint2 p = { pk2(a.x, a.y), pk2(a.z, a.w) };
        int gc = cs * 8 + ct;
        int s = ((gc >> 2) * 4 + (w & 3)) * 4 + (gc & 3);
        *(uint2*)&PO[pbase + (size_t)(s * 64 + lane) * 4] = p;
    }
}

// ---------------------------------------------------------------------------
// Kernel 3 (unchanged): sum JSPLIT partials, normalize, transpose,
// out = gamma * o + x. grid (64 i-tiles, 4 c-quarters, 4 b), block 256.
// ---------------------------------------------------------------------------
__global__ __launch_bounds__(256) void reduce_kernel(
    const __bf16* __restrict__ PO, const float* __restrict__ PL,
    const float* __restrict__ x, const float* __restrict__ gamma,
    float* __restrict__ out)
{
    __shared__ __align__(16) float oT[64 * 68];   // 17.4 KB
    __shared__ float sLinv[64];

    const int tid = threadIdx.x;
    const int iblk = blockIdx.x, wq = blockIdx.y, b = blockIdx.z;
    const int i0 = iblk * 64;
    const int lane = tid & 63, ct = tid >> 6, l15 = lane & 15, l4 = lane >> 4;

    if (tid < 64) {
        float l = 0.f;
#pragma unroll
        for (int js = 0; js < JSPLIT; ++js)
            l += PL[(size_t)(js * Bb + b) * Nn + i0 + tid];
        sLinv[tid] = 1.0f / l;
    }

    float o[4][4];
#pragma unroll
    for (int it = 0; it < 4; ++it) {
        o[it][0] = o[it][1] = o[it][2] = o[it][3] = 0.f;
#pragma unroll
        for (int js = 0; js < JSPLIT; ++js) {
            size_t base = (size_t)((js * Bb + b) * (Nn / 64) + iblk) * 16384;
            uint2 v = *(const uint2*)&PO[base + (size_t)((((wq * 4 + it) * 4 + ct) * 64 + lane)) * 4];
            o[it][0] += blo(v.x); o[it][1] += bhi(v.x);
            o[it][2] += blo(v.y); o[it][3] += bhi(v.y);
        }
    }

    const int cl = ct * 16 + l15;
#pragma unroll
    for (int it = 0; it < 4; ++it) {
        float4 t4 = { o[it][0], o[it][1], o[it][2], o[it][3] };
        *(float4*)&oT[cl * 68 + it * 16 + l4 * 4] = t4;
    }
    __syncthreads();

    const float g = gamma[0];
    const int c_l = tid >> 2, icol = (tid & 3) * 16;
    const int cg = wq * 64 + c_l;
    const size_t gb = (size_t)(b * Cc + cg) * Nn + i0 + icol;
#pragma unroll
    for (int k4 = 0; k4 < 4; ++k4) {
        float4 ov = *(const float4*)&oT[c_l * 68 + icol + k4 * 4];
        float4 li = *(const float4*)&sLinv[icol + k4 * 4];
        float4 xv = *(const float4*)&x[gb + k4 * 4];
        float4 res;
        res.x = fmaf(g, ov.x * li.x, xv.x);
        res.y = fmaf(g, ov.y * li.y, xv.y);
        res.z = fmaf(g, ov.z * li.z, xv.z);
        res.w = fmaf(g, ov.w * li.w, xv.w);
        *(float4*)&out[gb + k4 * 4] = res;
    }
}

// ---------------------------------------------------------------------------
extern "C" void kernel_launch(void* const* d_in, const int* in_sizes, int n_in,
                              void* d_out, int out_size, void* d_ws, size_t ws_size,
                              hipStream_t stream)
{
    const float* x    = (const float*)d_in[0];
    const float* wq   = (const float*)d_in[1];
    const float* wk   = (const float*)d_in[2];
    const float* wv   = (const float*)d_in[3];
    const float* bn1s = (const float*)d_in[4];
    const float* bn1b = (const float*)d_in[5];
    const float* bn1m = (const float*)d_in[6];
    const float* bn1v = (const float*)d_in[7];
    const float* bn2s = (const float*)d_in[8];
    const float* bn2b = (const float*)d_in[9];
    const float* bn2m = (const float*)d_in[10];
    const float* bn2v = (const float*)d_in[11];
    const float* bn3s = (const float*)d_in[12];
    const float* bn3b = (const float*)d_in[13];
    const float* bn3m = (const float*)d_in[14];
    const float* bn3v = (const float*)d_in[15];
    const float* gmm  = (const float*)d_in[16];
    float* out = (float*)d_out;

    // workspace layout (bytes), 43 MB total:
    // [Qt 1M][Kt 1M][Vb 8M][PO 16M @10M][PL 128K @26M][Wf 160K @26.25M]
    // [xhi 8M @27M][xlo 8M @35M]
    char* ws = (char*)d_ws;
    __bf16* Qt  = (__bf16*)(ws);
    __bf16* Kt  = (__bf16*)(ws + (1u << 20));
    __bf16* Vb  = (__bf16*)(ws + (2u << 20));
    __bf16* PO  = (__bf16*)(ws + (10u << 20));
    float*  PL  = (float*)(ws + (26u << 20));
    __bf16* Wf  = (__bf16*)(ws + (26u << 20) + 262144);
    __bf16* xhi = (__bf16*)(ws + (27u << 20));
    __bf16* xlo = (__bf16*)(ws + (35u << 20));

    prep_kernel<<<dim3(Nn / 64, 5, Bb), 256, 0, stream>>>(
        x, xhi, xlo, wq, wk, wv, Wf);

    qkv_kernel<<<dim3(Nn / 128, 3, Bb), 256, 0, stream>>>(
        xhi, xlo, Wf,
        bn1s, bn1b, bn1m, bn1v,
        bn2s, bn2b, bn2m, bn2v,
        bn3s, bn3b, bn3m, bn3v,
        Qt, Kt, Vb);

    attn_kernel<<<dim3(Nn / 128, JSPLIT * 2, Bb), 512, 0, stream>>>(Qt, Kt, Vb, PO, PL);

    reduce_kernel<<<dim3(Nn / 64, 4, Bb), 256, 0, stream>>>(PO, PL, x, gmm, out);
}

// Round 15
// 201.963 us; speedup vs baseline: 1.9361x; 1.9361x over previous
//
#include <hip/hip_runtime.h>

// Fixed problem sizes: b=4, c=256, n=4096, cr=32.
#define Bb 4
#define Cc 256
#define Nn 4096
#define CR 32
#define EPS_BN 1e-5f
// Fixed-shift softmax: scores >= 0 (post-ReLU Q,K), bounded << 100, so
// exp(s-20) is exactly softmax-equivalent and overflow/underflow safe.
// K is pre-scaled by log2(e) in qkv, so attn uses exp2(s' - 20*log2e).
#define SHIFT2 28.853900817779268f
#define LOG2E  1.4426950408889634f
#define JSPLIT 2
#define JSL (Nn / JSPLIT)    // 2048 j per attention block
#define TJ 128               // j-tile (8 waves x 16 j each)
#define NTILES (JSL / TJ)    // 16

typedef __attribute__((ext_vector_type(8))) short short8;   // 8 bf16
typedef __attribute__((ext_vector_type(4))) float f32x4;

__device__ inline unsigned int pk2(float a, float b) {
    __bf16 ha = (__bf16)a, hb = (__bf16)b;
    unsigned short ra = __builtin_bit_cast(unsigned short, ha);
    unsigned short rb = __builtin_bit_cast(unsigned short, hb);
    return ((unsigned int)rb << 16) | ra;
}
__device__ inline float blo(unsigned int u) { return __uint_as_float(u << 16); }
__device__ inline float bhi(unsigned int u) { return __uint_as_float(u & 0xffff0000u); }
__device__ inline float ex2(float x) { return __builtin_amdgcn_exp2f(x); }

// ---------------------------------------------------------------------------
// Kernel 0 (R13): fused preprocessing. Planes y=0..3: split-bf16 transpose of
// x -> xhi/xlo [b][n][c] (identical rounding to the original in-qkv split).
// Plane y=4 (z=0, x<20): pack W into frag-major bf16 Wf (160 KB, L2-hot).
// grid (64, 5, 4), 256 threads.
// ---------------------------------------------------------------------------
__global__ __launch_bounds__(256) void prep_kernel(
    const float* __restrict__ x,
    __bf16* __restrict__ xhi, __bf16* __restrict__ xlo,
    const float* __restrict__ wq, const float* __restrict__ wk,
    const float* __restrict__ wv, __bf16* __restrict__ Wf)
{
    __shared__ __align__(16) float tile[64][68];   // 17.4 KB
    const int tid = threadIdx.x;

    if (blockIdx.y == 4) {
        if (blockIdx.z != 0 || blockIdx.x >= 20) return;
        const int r16 = blockIdx.x;                 // 0..19
#pragma unroll
        for (int ss = 0; ss < 2; ++ss) {
            int s = tid + ss * 256;                 // 0..511 = (kc 8) x (lane 64)
            int kc = s >> 6, lane = s & 63;
            int R = r16 * 16 + (lane & 15);
            const float* src = (R < 32) ? (wq + (size_t)R * Cc)
                             : (R < 64) ? (wk + (size_t)(R - 32) * Cc)
                                        : (wv + (size_t)(R - 64) * Cc);
            const float* p = src + kc * 32 + (lane >> 4) * 8;
            float4 a = *(const float4*)p;
            float4 c2 = *(const float4*)(p + 4);
            uint4 pk = { pk2(a.x,a.y), pk2(a.z,a.w), pk2(c2.x,c2.y), pk2(c2.z,c2.w) };
            *(uint4*)&Wf[(((size_t)r16 * 8 + kc) * 64 + lane) * 8] = pk;
        }
        return;
    }

    const int n0 = blockIdx.x * 64, c0 = blockIdx.y * 64, b = blockIdx.z;

    {
        int r = tid >> 2, q = tid & 3;
        const float* src = &x[(size_t)(b * Cc + c0 + r) * Nn + n0 + q * 16];
#pragma unroll
        for (int u = 0; u < 4; ++u)
            *(float4*)&tile[r][q * 16 + u * 4] = *(const float4*)&src[u * 4];
    }
    __syncthreads();

    {
        int nr = tid >> 2, oc = tid & 3;
        uint4 H[2], L[2];
#pragma unroll
        for (int u = 0; u < 2; ++u) {
            float h[8], lo8[8];
#pragma unroll
            for (int j = 0; j < 8; ++j) {
                float v = tile[oc * 16 + u * 8 + j][nr];
                float hh = (float)(__bf16)v;
                h[j] = hh; lo8[j] = v - hh;
            }
            H[u] = (uint4){ pk2(h[0],h[1]), pk2(h[2],h[3]), pk2(h[4],h[5]), pk2(h[6],h[7]) };
            L[u] = (uint4){ pk2(lo8[0],lo8[1]), pk2(lo8[2],lo8[3]), pk2(lo8[4],lo8[5]), pk2(lo8[6],lo8[7]) };
        }
        size_t base = (size_t)(b * Nn + n0 + nr) * Cc + c0 + oc * 16;
        *(uint4*)&xhi[base]     = H[0];
        *(uint4*)&xhi[base + 8] = H[1];
        *(uint4*)&xlo[base]     = L[0];
        *(uint4*)&xlo[base + 8] = L[1];
    }
}

// ---------------------------------------------------------------------------
// Kernel 1 (R11): QKV = BN_ReLU(W x) as a pure global-operand GEMM.
// B-frags straight from xhi/xlo [b][n][c] (b128, L2-hot, reused by all 3
// groups); A-frags from Wf. No LDS/barriers in the K-loop.
// grid (32 n-tiles, 3 groups, 4 b), block 256.
// ---------------------------------------------------------------------------
__global__ __launch_bounds__(256) void qkv_kernel(
    const __bf16* __restrict__ xhi, const __bf16* __restrict__ xlo,
    const __bf16* __restrict__ Wf,
    const float* __restrict__ bn1s, const float* __restrict__ bn1b, const float* __restrict__ bn1m, const float* __restrict__ bn1v,
    const float* __restrict__ bn2s, const float* __restrict__ bn2b, const float* __restrict__ bn2m, const float* __restrict__ bn2v,
    const float* __restrict__ bn3s, const float* __restrict__ bn3b, const float* __restrict__ bn3m, const float* __restrict__ bn3v,
    __bf16* __restrict__ Qt, __bf16* __restrict__ Kt, __bf16* __restrict__ Vb)
{
    __shared__ __align__(16) __bf16 oT[128 * 136];         // V epilogue, 34 KB

    const int tid = threadIdx.x;
    const int n0 = blockIdx.x * 128, g = blockIdx.y, b = blockIdx.z;
    const int lane = tid & 63, w = tid >> 6;
    const int l15 = lane & 15, l4 = lane >> 4;
    const int nmt = (g == 0) ? 4 : 8;                       // row-16-groups
    const int r16b = (g == 0) ? 0 : 4 + (g - 1) * 8;        // base into Wf

    const size_t bfoff = (size_t)(b * Nn + n0 + w * 32 + l15) * Cc + l4 * 8;
    const __bf16* bh0 = xhi + bfoff;
    const __bf16* bl0 = xlo + bfoff;

    f32x4 acc[8][2];
#pragma unroll
    for (int mt = 0; mt < 8; ++mt)
#pragma unroll
        for (int nt = 0; nt < 2; ++nt) acc[mt][nt] = (f32x4){0.f, 0.f, 0.f, 0.f};

    for (int kc = 0; kc < 8; ++kc) {
        short8 bh[2], bl[2];
#pragma unroll
        for (int nt = 0; nt < 2; ++nt) {
            bh[nt] = *(const short8*)&bh0[(size_t)(nt * 16) * Cc + kc * 32];
            bl[nt] = *(const short8*)&bl0[(size_t)(nt * 16) * Cc + kc * 32];
        }
#pragma unroll
        for (int mt = 0; mt < 8; ++mt) {
            if (mt < nmt) {
                short8 af = *(const short8*)&Wf[(((size_t)(r16b + mt) * 8 + kc) * 64 + lane) * 8];
#pragma unroll
                for (int nt = 0; nt < 2; ++nt) {
                    acc[mt][nt] = __builtin_amdgcn_mfma_f32_16x16x32_bf16(af, bh[nt], acc[mt][nt], 0, 0, 0);
                    acc[mt][nt] = __builtin_amdgcn_mfma_f32_16x16x32_bf16(af, bl[nt], acc[mt][nt], 0, 0, 0);
                }
            }
        }
    }

    if (g == 0) {
#pragma unroll
        for (int mt = 0; mt < 4; ++mt) {
            float scl[4], off[4];
#pragma unroll
            for (int r = 0; r < 4; ++r) {
                int R = mt * 16 + l4 * 4 + r;
                float s, o;
                if (R < 32) {
                    s = bn1s[R] * __frsqrt_rn(bn1v[R] + EPS_BN);
                    o = bn1b[R] - bn1m[R] * s;
                } else {
                    int row = R - 32;
                    s = bn2s[row] * __frsqrt_rn(bn2v[row] + EPS_BN);
                    o = bn2b[row] - bn2m[row] * s;
                    s *= LOG2E; o *= LOG2E;
                }
                scl[r] = s; off[r] = o;
            }
            __bf16* dst = (mt < 2) ? Qt : Kt;
            int d0 = (mt & 1) * 16 + l4 * 4;
#pragma unroll
            for (int nt = 0; nt < 2; ++nt) {
                f32x4 a = acc[mt][nt];
                float e0 = fmaxf(fmaf(a.x, scl[0], off[0]), 0.f);
                float e1 = fmaxf(fmaf(a.y, scl[1], off[1]), 0.f);
                float e2 = fmaxf(fmaf(a.z, scl[2], off[2]), 0.f);
                float e3 = fmaxf(fmaf(a.w, scl[3], off[3]), 0.f);
                uint2 p = { pk2(e0, e1), pk2(e2, e3) };
                int n = n0 + w * 32 + nt * 16 + l15;
                *(uint2*)&dst[(size_t)(b * Nn + n) * CR + d0] = p;
            }
        }
    } else {
        const int vr0 = (g - 1) * 128;
#pragma unroll
        for (int mt = 0; mt < 8; ++mt) {
            float scl[4], off[4];
#pragma unroll
            for (int r = 0; r < 4; ++r) {
                int row = vr0 + mt * 16 + l4 * 4 + r;
                float s = bn3s[row] * __frsqrt_rn(bn3v[row] + EPS_BN);
                scl[r] = s; off[r] = bn3b[row] - bn3m[row] * s;
            }
#pragma unroll
            for (int nt = 0; nt < 2; ++nt) {
                f32x4 a = acc[mt][nt];
                float e[4];
                e[0] = fmaxf(fmaf(a.x, scl[0], off[0]), 0.f);
                e[1] = fmaxf(fmaf(a.y, scl[1], off[1]), 0.f);
                e[2] = fmaxf(fmaf(a.z, scl[2], off[2]), 0.f);
                e[3] = fmaxf(fmaf(a.w, scl[3], off[3]), 0.f);
                int ncol = w * 32 + nt * 16 + l15;
#pragma unroll
                for (int r = 0; r < 4; ++r)
                    oT[(mt * 16 + l4 * 4 + r) * 136 + ncol] = (__bf16)e[r];
            }
        }
        __syncthreads();
        int rr = tid >> 1, qq = tid & 1;          // 128 rows x 2 n-halves
        size_t vrow = (size_t)(b * Cc + vr0 + rr) * Nn + n0 + qq * 64;
#pragma unroll
        for (int e8 = 0; e8 < 8; ++e8)
            *(uint4*)&Vb[vrow + e8 * 8] = *(const uint4*)&oT[rr * 136 + qq * 64 + e8 * 8];
    }
}

// ---------------------------------------------------------------------------
// Kernel 2 (R15 = best-measured R10/R11 attn, verbatim): 8-wave blocks,
// TJ=128, JSPLIT=2, 2-barrier skeleton, XOR-swizzled sP, qf in registers,
// vf 2-deep rotation, setprio on PV. 72.3-73.5 us measured across runs.
// grid (64 i-tiles, 2 js, 4 b) = 512 blocks, block 512 (8 waves).
// ---------------------------------------------------------------------------
__global__ __launch_bounds__(512) void attn_kernel(
    const __bf16* __restrict__ Qt, const __bf16* __restrict__ Kt,
    const __bf16* __restrict__ Vb,
    __bf16* __restrict__ PO, float* __restrict__ PL)
{
    __shared__ __align__(16) __bf16 sQ[64 * 40];    // 5.1 KB
    __shared__ __align__(16) __bf16 sP[64 * 128];   // 16 KB, XOR-swizzled rows
    __shared__ __align__(16) float  sL[8][64];      // 2 KB

    const int tid = threadIdx.x, lane = tid & 63, w = tid >> 6;   // w 0..7
    const int b = blockIdx.z, js = blockIdx.y, iblk = blockIdx.x;
    const int i0 = iblk * 64;
    const int l15 = lane & 15, l4 = lane >> 4;

    if (tid < 256) {
        int i = tid >> 2, o = tid & 3;
        *(uint4*)&sQ[i * 40 + o * 8] =
            *(const uint4*)&Qt[(size_t)(b * Nn + i0 + i) * CR + o * 8];
    }
    __syncthreads();

    short8 qf[4];
#pragma unroll
    for (int it = 0; it < 4; ++it)
        qf[it] = *(const short8*)&sQ[(it * 16 + l15) * 40 + l4 * 8];

    f32x4 oacc[8];
#pragma unroll
    for (int z = 0; z < 8; ++z) oacc[z] = (f32x4){0.f, 0.f, 0.f, 0.f};
    float lp[4] = {0.f, 0.f, 0.f, 0.f};

    const size_t jb = (size_t)js * JSL;
    short8 kf = *(const short8*)&Kt[(size_t)(b * Nn + jb + 16 * w + l15) * CR + l4 * 8];
    const __bf16* vrow0 = Vb + (size_t)(b * Cc + w * 32 + l15) * Nn;

    char* sPb = (char*)sP;
    const int wcolw = w * 32 + l4 * 8;              // write col (bytes), pre-XOR

    for (int t = 0; t < NTILES; ++t) {
        const size_t j0 = jb + (size_t)t * TJ;

        short8 v0[2], v1[2];
#pragma unroll
        for (int ct = 0; ct < 2; ++ct)
            v0[ct] = *(const short8*)&vrow0[(size_t)(ct * 16) * Nn + j0 + l4 * 8];
#pragma unroll
        for (int ct = 0; ct < 2; ++ct)
            v1[ct] = *(const short8*)&vrow0[(size_t)(ct * 16) * Nn + j0 + 32 + l4 * 8];

#pragma unroll
        for (int it = 0; it < 4; ++it) {
            f32x4 c0 = (f32x4){0.f, 0.f, 0.f, 0.f};
            c0 = __builtin_amdgcn_mfma_f32_16x16x32_bf16(kf, qf[it], c0, 0, 0, 0);
            float e0 = ex2(c0.x - SHIFT2);
            float e1 = ex2(c0.y - SHIFT2);
            float e2 = ex2(c0.z - SHIFT2);
            float e3 = ex2(c0.w - SHIFT2);
            lp[it] += (e0 + e1) + (e2 + e3);
            uint2 p2 = { pk2(e0, e1), pk2(e2, e3) };
            int row = it * 16 + l15;
            *(uint2*)(sPb + row * 256 + (wcolw ^ ((row & 7) << 4))) = p2;
        }
        __syncthreads();   // barrier A

        if (t + 1 < NTILES)
            kf = *(const short8*)&Kt[(size_t)(b * Nn + j0 + TJ + 16 * w + l15) * CR + l4 * 8];

        __builtin_amdgcn_s_setprio(1);
        {
            short8 pf[4];
#pragma unroll
            for (int it = 0; it < 4; ++it) {
                int row = it * 16 + l15;
                pf[it] = *(const short8*)(sPb + row * 256 + ((l4 * 16) ^ ((row & 7) << 4)));
            }
#pragma unroll
            for (int ct = 0; ct < 2; ++ct)
#pragma unroll
                for (int it = 0; it < 4; ++it)
                    oacc[it * 2 + ct] = __builtin_amdgcn_mfma_f32_16x16x32_bf16(
                        pf[it], v0[ct], oacc[it * 2 + ct], 0, 0, 0);
        }
#pragma unroll
        for (int ct = 0; ct < 2; ++ct)
            v0[ct] = *(const short8*)&vrow0[(size_t)(ct * 16) * Nn + j0 + 64 + l4 * 8];
        {
            short8 pf[4];
#pragma unroll
            for (int it = 0; it < 4; ++it) {
                int row = it * 16 + l15;
                pf[it] = *(const short8*)(sPb + row * 256 + ((64 + l4 * 16) ^ ((row & 7) << 4)));
            }
#pragma unroll
            for (int ct = 0; ct < 2; ++ct)
#pragma unroll
                for (int it = 0; it < 4; ++it)
                    oacc[it * 2 + ct] = __builtin_amdgcn_mfma_f32_16x16x32_bf16(
                        pf[it], v1[ct], oacc[it * 2 + ct], 0, 0, 0);
        }
#pragma unroll
        for (int ct = 0; ct < 2; ++ct)
            v1[ct] = *(const short8*)&vrow0[(size_t)(ct * 16) * Nn + j0 + 96 + l4 * 8];
        {
            short8 pf[4];
#pragma unroll
            for (int it = 0; it < 4; ++it) {
                int row = it * 16 + l15;
                pf[it] = *(const short8*)(sPb + row * 256 + ((128 + l4 * 16) ^ ((row & 7) << 4)));
            }
#pragma unroll
            for (int ct = 0; ct < 2; ++ct)
#pragma unroll
                for (int it = 0; it < 4; ++it)
                    oacc[it * 2 + ct] = __builtin_amdgcn_mfma_f32_16x16x32_bf16(
                        pf[it], v0[ct], oacc[it * 2 + ct], 0, 0, 0);
        }
        {
            short8 pf[4];
#pragma unroll
            for (int it = 0; it < 4; ++it) {
                int row = it * 16 + l15;
                pf[it] = *(const short8*)(sPb + row * 256 + ((192 + l4 * 16) ^ ((row & 7) << 4)));
            }
#pragma unroll
            for (int ct = 0; ct < 2; ++ct)
#pragma unroll
                for (int it = 0; it < 4; ++it)
                    oacc[it * 2 + ct] = __builtin_amdgcn_mfma_f32_16x16x32_bf16(
                        pf[it], v1[ct], oacc[it * 2 + ct], 0, 0, 0);
        }
        __builtin_amdgcn_s_setprio(0);
        __syncthreads();   // barrier B
    }

#pragma unroll
    for (int it = 0; it < 4; ++it) {
        float v = lp[it];
        v += __shfl_xor(v, 16);
        v += __shfl_xor(v, 32);
        if (lane < 16) sL[w][it * 16 + lane] = v;
    }
    __syncthreads();
    if (tid < 64) {
        float s = 0.f;
#pragma unroll
        for (int w8 = 0; w8 < 8; ++w8) s += sL[w8][tid];
        PL[(size_t)(js * Bb + b) * Nn + i0 + tid] = s;
    }

    const size_t base = (size_t)((js * Bb + b) * (Nn / 64) + iblk) * 16384;
#pragma unroll
    for (int it = 0; it < 4; ++it)
#pragma unroll
        for (int ct = 0; ct < 2; ++ct) {
            f32x4 a = oacc[it * 2 + ct];
            uint2 p = { pk2(a.x, a.y), pk2(a.z, a.w) };
            int g16 = w * 2 + ct;
            int s = (g16 >> 2) * 16 + it * 4 + (g16 & 3);
            *(uint2*)&PO[base + (size_t)(s * 64 + lane) * 4] = p;
        }
}

// ---------------------------------------------------------------------------
// Kernel 3 (unchanged): sum JSPLIT partials, normalize, transpose,
// out = gamma * o + x. grid (64 i-tiles, 4 c-quarters, 4 b), block 256.
// ---------------------------------------------------------------------------
__global__ __launch_bounds__(256) void reduce_kernel(
    const __bf16* __restrict__ PO, const float* __restrict__ PL,
    const float* __restrict__ x, const float* __restrict__ gamma,
    float* __restrict__ out)
{
    __shared__ __align__(16) float oT[64 * 68];   // 17.4 KB
    __shared__ float sLinv[64];

    const int tid = threadIdx.x;
    const int iblk = blockIdx.x, wq = blockIdx.y, b = blockIdx.z;
    const int i0 = iblk * 64;
    const int lane = tid & 63, ct = tid >> 6, l15 = lane & 15, l4 = lane >> 4;

    if (tid < 64) {
        float l = 0.f;
#pragma unroll
        for (int js = 0; js < JSPLIT; ++js)
            l += PL[(size_t)(js * Bb + b) * Nn + i0 + tid];
        sLinv[tid] = 1.0f / l;
    }

    float o[4][4];
#pragma unroll
    for (int it = 0; it < 4; ++it) {
        o[it][0] = o[it][1] = o[it][2] = o[it][3] = 0.f;
#pragma unroll
        for (int js = 0; js < JSPLIT; ++js) {
            size_t base = (size_t)((js * Bb + b) * (Nn / 64) + iblk) * 16384;
            uint2 v = *(const uint2*)&PO[base + (size_t)((((wq * 4 + it) * 4 + ct) * 64 + lane)) * 4];
            o[it][0] += blo(v.x); o[it][1] += bhi(v.x);
            o[it][2] += blo(v.y); o[it][3] += bhi(v.y);
        }
    }

    const int cl = ct * 16 + l15;
#pragma unroll
    for (int it = 0; it < 4; ++it) {
        float4 t4 = { o[it][0], o[it][1], o[it][2], o[it][3] };
        *(float4*)&oT[cl * 68 + it * 16 + l4 * 4] = t4;
    }
    __syncthreads();

    const float g = gamma[0];
    const int c_l = tid >> 2, icol = (tid & 3) * 16;
    const int cg = wq * 64 + c_l;
    const size_t gb = (size_t)(b * Cc + cg) * Nn + i0 + icol;
#pragma unroll
    for (int k4 = 0; k4 < 4; ++k4) {
        float4 ov = *(const float4*)&oT[c_l * 68 + icol + k4 * 4];
        float4 li = *(const float4*)&sLinv[icol + k4 * 4];
        float4 xv = *(const float4*)&x[gb + k4 * 4];
        float4 res;
        res.x = fmaf(g, ov.x * li.x, xv.x);
        res.y = fmaf(g, ov.y * li.y, xv.y);
        res.z = fmaf(g, ov.z * li.z, xv.z);
        res.w = fmaf(g, ov.w * li.w, xv.w);
        *(float4*)&out[gb + k4 * 4] = res;
    }
}

// ---------------------------------------------------------------------------
extern "C" void kernel_launch(void* const* d_in, const int* in_sizes, int n_in,
                              void* d_out, int out_size, void* d_ws, size_t ws_size,
                              hipStream_t stream)
{
    const float* x    = (const float*)d_in[0];
    const float* wq   = (const float*)d_in[1];
    const float* wk   = (const float*)d_in[2];
    const float* wv   = (const float*)d_in[3];
    const float* bn1s = (const float*)d_in[4];
    const float* bn1b = (const float*)d_in[5];
    const float* bn1m = (const float*)d_in[6];
    const float* bn1v = (const float*)d_in[7];
    const float* bn2s = (const float*)d_in[8];
    const float* bn2b = (const float*)d_in[9];
    const float* bn2m = (const float*)d_in[10];
    const float* bn2v = (const float*)d_in[11];
    const float* bn3s = (const float*)d_in[12];
    const float* bn3b = (const float*)d_in[13];
    const float* bn3m = (const float*)d_in[14];
    const float* bn3v = (const float*)d_in[15];
    const float* gmm  = (const float*)d_in[16];
    float* out = (float*)d_out;

    // workspace layout (bytes), 43 MB total:
    // [Qt 1M][Kt 1M][Vb 8M][PO 16M @10M][PL 128K @26M][Wf 160K @26.25M]
    // [xhi 8M @27M][xlo 8M @35M]
    char* ws = (char*)d_ws;
    __bf16* Qt  = (__bf16*)(ws);
    __bf16* Kt  = (__bf16*)(ws + (1u << 20));
    __bf16* Vb  = (__bf16*)(ws + (2u << 20));
    __bf16* PO  = (__bf16*)(ws + (10u << 20));
    float*  PL  = (float*)(ws + (26u << 20));
    __bf16* Wf  = (__bf16*)(ws + (26u << 20) + 262144);
    __bf16* xhi = (__bf16*)(ws + (27u << 20));
    __bf16* xlo = (__bf16*)(ws + (35u << 20));

    prep_kernel<<<dim3(Nn / 64, 5, Bb), 256, 0, stream>>>(
        x, xhi, xlo, wq, wk, wv, Wf);

    qkv_kernel<<<dim3(Nn / 128, 3, Bb), 256, 0, stream>>>(
        xhi, xlo, Wf,
        bn1s, bn1b, bn1m, bn1v,
        bn2s, bn2b, bn2m, bn2v,
        bn3s, bn3b, bn3m, bn3v,
        Qt, Kt, Vb);

    attn_kernel<<<dim3(Nn / 64, JSPLIT, Bb), 512, 0, stream>>>(Qt, Kt, Vb, PO, PL);

    reduce_kernel<<<dim3(Nn / 64, 4, Bb), 256, 0, stream>>>(PO, PL, x, gmm, out);
}